// Round 16
// baseline (64.309 us; speedup 1.0000x reference)
//
#include <hip/hip_runtime.h>

// Problem sizes
#define NB  131072
#define ND1 40
#define ND2 10
#define NT0 120
#define NT1 5
#define NO0 3

#define NBT 16                  // batches per tile
#define TPB 4                   // tiles per block (grid 2048 blocks)
#define XTILE (NBT * ND1 * ND2) // 6400 floats = 25600 B per tile
#define PK  40                  // Ybf row pitch (bf16 elems)
#define CHUNKS 25               // 1KB staging chunks per tile
#define LPW 7                   // gload_lds per wave per tile (7*4=28>=25, clamped)

typedef __attribute__((ext_vector_type(8))) short  short8;
typedef __attribute__((ext_vector_type(4))) float  f32x4;
typedef unsigned int u32;

static __device__ __forceinline__ unsigned short f2bf(float f) {
    union { float f; unsigned u; } v; v.f = f;
    unsigned r = v.u + 0x7FFFu + ((v.u >> 16) & 1u);
    return (unsigned short)(r >> 16);
}

// Counted-vmcnt double-buffered pipeline (T3+T4): per tile, issue next tile's
// stage (7 gload_lds/wave, uniform), wait vmcnt(7) = previous tile's loads
// only, raw s_barrier (NO vmcnt drain). All other global traffic hoisted to
// the prologue so the vmcnt FIFO stays exactly {stores, stage}.
__global__ __launch_bounds__(256, 2) void BL_36721970381090_kernel(
    const float* __restrict__ x,
    const float* __restrict__ W11,
    const float* __restrict__ fc2_w,
    const float* __restrict__ bias1,
    const float* __restrict__ W12,
    const float* __restrict__ fc4_w,
    const float* __restrict__ bias2,
    float* __restrict__ out)
{
    __shared__ __align__(16) float xsA[XTILE];                   // 25600 B
    __shared__ __align__(16) float xsB[XTILE];                   // 25600 B
    __shared__ __align__(16) unsigned short Ybf[NT1 * NBT * PK]; //  6400 B
    __shared__ float biasL[128 * NT1];                           //  2560 B (t-padded)
    __shared__ float w12L[NO0 * 128];                            //  1536 B (t-padded)
    __shared__ float fc2L[64];                                   //   256 B
    __shared__ float b2L[4];
    __shared__ float redL[4 * NO0 * NBT];                        //   768 B

    const int tid = threadIdx.x;
    const int w   = tid >> 6;   // wave 0..3
    const int l   = tid & 63;
    const int lr  = l & 15;
    const int lg  = l >> 4;
    const int tile0 = blockIdx.x * TPB;

    // ---------------- prologue: constants -> LDS / registers -------------
    for (int i = tid; i < 128 * NT1; i += 256)
        biasL[i] = (i < NT0 * NT1) ? bias1[i] : 0.f;
    for (int i = tid; i < NO0 * 128; i += 256) {
        const int o = i >> 7, t = i & 127;
        w12L[i] = (t < NT0) ? W12[o * NT0 + t] : 0.f;
    }
    if (tid < NT1 * ND2) fc2L[tid] = fc2_w[tid];
    if (tid < NO0) b2L[tid] = bias2[tid];

    float fc4r[NT1];
#pragma unroll
    for (int u = 0; u < NT1; ++u) fc4r[u] = fc4_w[u];   // waits resolve here

    // A-fragments: W11 -> bf16, masked (t<120, d<40); vmcnt resolved by cvts
    short8 afr[2][2];
#pragma unroll
    for (int mt = 0; mt < 2; ++mt) {
        const int t  = w * 32 + mt * 16 + lr;
        const int tc = t < NT0 ? t : NT0 - 1;
#pragma unroll
        for (int kk = 0; kk < 2; ++kk) {
            const int cb = kk * 32 + lg * 8;
            const int cc = cb <= 32 ? cb : 0;
            const float4* pw = (const float4*)(W11 + tc * ND1 + cc);
            const float4 w0 = pw[0], w1 = pw[1];
            const bool v = (t < NT0) && (cb <= 32);
            short8 f;
            f[0] = v ? (short)f2bf(w0.x) : (short)0;
            f[1] = v ? (short)f2bf(w0.y) : (short)0;
            f[2] = v ? (short)f2bf(w0.z) : (short)0;
            f[3] = v ? (short)f2bf(w0.w) : (short)0;
            f[4] = v ? (short)f2bf(w1.x) : (short)0;
            f[5] = v ? (short)f2bf(w1.y) : (short)0;
            f[6] = v ? (short)f2bf(w1.z) : (short)0;
            f[7] = v ? (short)f2bf(w1.w) : (short)0;
            afr[mt][kk] = f;
        }
    }

    // stage macro: exactly LPW gload_lds per wave (chunk id clamped)
    auto STAGE = [&](float* lbuf, int tile) {
        const char* g  = (const char*)(x + (size_t)(tile0 + tile) * XTILE);
        char*       lb = (char*)lbuf;
#pragma unroll
        for (int i = 0; i < LPW; ++i) {
            int j = w * LPW + i;
            if (j >= CHUNKS) j = CHUNKS - 1;          // clamp: same data, benign
            const float* gp = (const float*)(g + j * 1024 + l * 16);
            __builtin_amdgcn_global_load_lds(
                (const u32 __attribute__((address_space(1)))*)gp,
                (u32 __attribute__((address_space(3)))*)(lb + j * 1024),
                16, 0, 0);
        }
    };

    STAGE(xsA, 0);   // tile 0 in flight

    for (int t = 0; t < TPB; ++t) {
        const float* cur = (t & 1) ? xsB : xsA;
        float*       nxt = (t & 1) ? xsA : xsB;
        const int tn = (t + 1 < TPB) ? t + 1 : TPB - 1;   // uniform count
        STAGE(nxt, tn);

        asm volatile("s_waitcnt vmcnt(7)" ::: "memory");   // tile t ready
        asm volatile("s_waitcnt lgkmcnt(0)" ::: "memory");
        __builtin_amdgcn_s_barrier();                      // no vmcnt drain

        // ---------------- phase 1: y from LDS, write bf16 Y --------------
        {
            unsigned* Yw = (unsigned*)Ybf;
#pragma unroll
            for (int rep = 0; rep < 2; ++rep) {
                const int  q   = (rep == 0) ? tid : (256 + (tid >> 2));
                const bool act = (rep == 0) || ((tid & 3) == 0);
                if (act) {                       // 320 2-row units
                    const int batch = q / 20;
                    const int pair  = q - batch * 20;
                    float4 xq[5];
                    const float4* xr = (const float4*)(cur + batch * 400 + pair * 20);
#pragma unroll
                    for (int i = 0; i < 5; ++i) xq[i] = xr[i];
                    const float* xv = (const float*)xq;
#pragma unroll
                    for (int u = 0; u < NT1; ++u) {
                        float a0 = 0.f, a1 = 0.f;
#pragma unroll
                        for (int s = 0; s < ND2; ++s) {
                            const float fw = fc2L[u * ND2 + s];
                            a0 = fmaf(xv[s], fw, a0);
                            a1 = fmaf(xv[10 + s], fw, a1);
                        }
                        Yw[u * (NBT * PK / 2) + batch * (PK / 2) + pair] =
                            (unsigned)f2bf(a0) | ((unsigned)f2bf(a1) << 16);
                    }
                }
            }
        }
        asm volatile("s_waitcnt lgkmcnt(0)" ::: "memory");
        __builtin_amdgcn_s_barrier();                      // Ybf visible

        // ---------------- phase 2: MFMA + fused relu/fc4 -----------------
        float st[2][4];
#pragma unroll
        for (int mt = 0; mt < 2; ++mt)
#pragma unroll
            for (int r = 0; r < 4; ++r) st[mt][r] = 0.f;

        const short8 zf = {0, 0, 0, 0, 0, 0, 0, 0};
#pragma unroll
        for (int u = 0; u < NT1; ++u) {
            float bv[2][4];
#pragma unroll
            for (int mt = 0; mt < 2; ++mt)
#pragma unroll
                for (int r = 0; r < 4; ++r)
                    bv[mt][r] = biasL[(w * 32 + mt * 16 + lg * 4 + r) * NT1 + u];
            const unsigned short* Yu = &Ybf[u * (NBT * PK)];
            const short8 b0 = *(const short8*)&Yu[lr * PK + lg * 8];
            short8 b1 = zf;
            if (lg == 0) b1 = *(const short8*)&Yu[lr * PK + 32];
#pragma unroll
            for (int mt = 0; mt < 2; ++mt) {
                f32x4 z = {0.f, 0.f, 0.f, 0.f};
                z = __builtin_amdgcn_mfma_f32_16x16x32_bf16(afr[mt][0], b0, z, 0, 0, 0);
                z = __builtin_amdgcn_mfma_f32_16x16x32_bf16(afr[mt][1], b1, z, 0, 0, 0);
#pragma unroll
                for (int r = 0; r < 4; ++r)
                    st[mt][r] += fc4r[u] * fmaxf(z[r] + bv[mt][r], 0.f);
            }
        }

        // ---------------- epilogue: out[o,b] = sum_t W12[o,t]*st ---------
        float po[NO0];
#pragma unroll
        for (int o = 0; o < NO0; ++o) {
            float a = 0.f;
#pragma unroll
            for (int mt = 0; mt < 2; ++mt)
#pragma unroll
                for (int r = 0; r < 4; ++r)
                    a = fmaf(w12L[o * 128 + (w * 32 + mt * 16 + lg * 4 + r)],
                             st[mt][r], a);
            a += __shfl_xor(a, 16, 64);
            a += __shfl_xor(a, 32, 64);
            po[o] = a;
        }
        if (l < 16) {
#pragma unroll
            for (int o = 0; o < NO0; ++o)
                redL[(w * NO0 + o) * NBT + l] = po[o];
        }
        asm volatile("s_waitcnt lgkmcnt(0)" ::: "memory");
        __builtin_amdgcn_s_barrier();

        if (tid < NO0 * NBT) {                    // 48 threads (wave 0 only)
            const int o  = tid >> 4;
            const int bc = tid & 15;
            const float s = redL[(0 * NO0 + o) * NBT + bc]
                          + redL[(1 * NO0 + o) * NBT + bc]
                          + redL[(2 * NO0 + o) * NBT + bc]
                          + redL[(3 * NO0 + o) * NBT + bc]
                          + b2L[o];
            out[((size_t)(tile0 + t) * NBT + bc) * NO0 + o] = s;
        }
    }
}

extern "C" void kernel_launch(void* const* d_in, const int* in_sizes, int n_in,
                              void* d_out, int out_size, void* d_ws, size_t ws_size,
                              hipStream_t stream) {
    const float* x      = (const float*)d_in[0];
    const float* W11    = (const float*)d_in[1];
    const float* fc2_w  = (const float*)d_in[2];
    const float* bias1  = (const float*)d_in[3];
    const float* W12    = (const float*)d_in[4];
    const float* fc4_w  = (const float*)d_in[5];
    const float* bias2  = (const float*)d_in[6];
    float* out = (float*)d_out;

    const int blocks = NB / (NBT * TPB);   // 2048
    BL_36721970381090_kernel<<<blocks, 256, 0, stream>>>(
        x, W11, fc2_w, bias1, W12, fc4_w, bias2, out);
}

// Round 17
// 62.376 us; speedup vs baseline: 1.0310x; 1.0310x over previous
//
#include <hip/hip_runtime.h>

// Problem sizes
#define NB  131072
#define ND1 40
#define ND2 10
#define NT0 120
#define NT1 5
#define NO0 3

#define NBW 16                  // batches per workgroup
#define XTILE (NBW * ND1 * ND2) // 6400 floats = 25600 B
#define PK  40                  // Ybf row pitch (bf16 elems)
#define CHUNKS 25               // 1KB staging chunks

typedef __attribute__((ext_vector_type(8))) short  short8;
typedef __attribute__((ext_vector_type(4))) float  f32x4;
typedef unsigned int u32;

static __device__ __forceinline__ unsigned short f2bf(float f) {
    union { float f; unsigned u; } v; v.f = f;
    unsigned r = v.u + 0x7FFFu + ((v.u >> 16) & 1u);
    return (unsigned short)(r >> 16);
}

// One 16-batch tile per 256-thread block; 8192 blocks.
// LDS ~37 KB -> 4 blocks/CU (vs R15's 64 KB -> 2): doubles resident waves,
// which is the mechanism that carried 74.6->62.5 µs (cross-block overlap of
// stage-HBM and compute). In-block pipelining measured null (R16).
//  stage:   x tile -> LDS via 25 coalesced 1KB global_load_lds chunks.
//  phase 1: 320 (batch,row-pair) units; y -> bf16 Y[u][b][d] in LDS.
//  phase 2: MFMA bf16: Z[t,b]=sum_d W11[t,d]*Y_u[d,b];
//           st += fc4[u]*relu(Z+bias1).  (t padded to 128, d to 64.)
//  epilogue: out[o,b] = sum_t W12[o,t]*st[t,b].
__global__ __launch_bounds__(256, 2) void BL_36721970381090_kernel(
    const float* __restrict__ x,
    const float* __restrict__ W11,
    const float* __restrict__ fc2_w,
    const float* __restrict__ bias1,
    const float* __restrict__ W12,
    const float* __restrict__ fc4_w,
    const float* __restrict__ bias2,
    float* __restrict__ out)
{
    __shared__ __align__(16) float xs[XTILE];                    // 25600 B
    __shared__ __align__(16) unsigned short Ybf[NT1 * NBW * PK]; //  6400 B
    __shared__ float biasL[128 * NT1];                           //  2560 B
    __shared__ float w12L[NO0 * 128];                            //  1536 B
    __shared__ float fc2L[64];                                   //   256 B
    __shared__ float b2L[4];
    __shared__ float redL[4 * NO0 * NBW];                        //   768 B

    const int tid = threadIdx.x;
    const int wg  = blockIdx.x;
    const int w   = tid >> 6;   // wave 0..3
    const int l   = tid & 63;
    const int lr  = l & 15;     // A row / B col within 16-tile
    const int lg  = l >> 4;     // k-group

    // ---------------- stage: x tile -> LDS, coalesced -------------------
    {
        const char* gbase = (const char*)(x + (size_t)wg * XTILE);
        char* lbase = (char*)xs;
#pragma unroll
        for (int i = 0; i < 7; ++i) {
            const int j = i * 4 + w;                  // wave-uniform chunk id
            if (j < CHUNKS) {
                const float* g = (const float*)(gbase + j * 1024 + l * 16);
                __builtin_amdgcn_global_load_lds(
                    (const u32 __attribute__((address_space(1)))*)g,
                    (u32 __attribute__((address_space(3)))*)(lbase + j * 1024),
                    16, 0, 0);
            }
        }
    }

    // ---------------- prologue: constants -> LDS (overlaps stage) --------
    for (int i = tid; i < 128 * NT1; i += 256)
        biasL[i] = (i < NT0 * NT1) ? bias1[i] : 0.f;
    for (int i = tid; i < NO0 * 128; i += 256) {
        const int o = i >> 7, t = i & 127;
        w12L[i] = (t < NT0) ? W12[o * NT0 + t] : 0.f;
    }
    if (tid < NT1 * ND2) fc2L[tid] = fc2_w[tid];
    if (tid < NO0) b2L[tid] = bias2[tid];

    float fc4r[NT1];
#pragma unroll
    for (int u = 0; u < NT1; ++u) fc4r[u] = fc4_w[u];

    // A-fragments: W11 -> bf16, masked (t<120, d<40)
    short8 afr[2][2];
#pragma unroll
    for (int mt = 0; mt < 2; ++mt) {
        const int t  = w * 32 + mt * 16 + lr;
        const int tc = t < NT0 ? t : NT0 - 1;
#pragma unroll
        for (int kk = 0; kk < 2; ++kk) {
            const int cb = kk * 32 + lg * 8;
            const int cc = cb <= 32 ? cb : 0;
            const float4* pw = (const float4*)(W11 + tc * ND1 + cc);
            const float4 w0 = pw[0], w1 = pw[1];
            const bool v = (t < NT0) && (cb <= 32);
            short8 f;
            f[0] = v ? (short)f2bf(w0.x) : (short)0;
            f[1] = v ? (short)f2bf(w0.y) : (short)0;
            f[2] = v ? (short)f2bf(w0.z) : (short)0;
            f[3] = v ? (short)f2bf(w0.w) : (short)0;
            f[4] = v ? (short)f2bf(w1.x) : (short)0;
            f[5] = v ? (short)f2bf(w1.y) : (short)0;
            f[6] = v ? (short)f2bf(w1.z) : (short)0;
            f[7] = v ? (short)f2bf(w1.w) : (short)0;
            afr[mt][kk] = f;
        }
    }

    __syncthreads();   // x tile + constants visible

    // ---------------- phase 1: y from LDS, write bf16 Y ------------------
    {
        unsigned* Yw = (unsigned*)Ybf;
#pragma unroll
        for (int rep = 0; rep < 2; ++rep) {
            const int  q   = (rep == 0) ? tid : 256 + tid;  // unit id
            const bool act = (rep == 0) || (tid < 64);
            if (act) {                                // 320 (batch,pair) units
                const int batch = q / 20;
                const int pair  = q - batch * 20;     // d-pair 0..19
                float4 xq[5];
                const float4* xr = (const float4*)(xs + batch * 400 + pair * 20);
#pragma unroll
                for (int i = 0; i < 5; ++i) xq[i] = xr[i];
                const float* xv = (const float*)xq;
#pragma unroll
                for (int u = 0; u < NT1; ++u) {
                    float a0 = 0.f, a1 = 0.f;
#pragma unroll
                    for (int s = 0; s < ND2; ++s) {
                        const float fw = fc2L[u * ND2 + s];
                        a0 = fmaf(xv[s], fw, a0);
                        a1 = fmaf(xv[10 + s], fw, a1);
                    }
                    Yw[u * (NBW * PK / 2) + batch * (PK / 2) + pair] =
                        (unsigned)f2bf(a0) | ((unsigned)f2bf(a1) << 16);
                }
            }
        }
    }
    __syncthreads();   // Ybf visible

    // ---------------- phase 2: MFMA + fused relu/fc4 ---------------------
    float st[2][4];
#pragma unroll
    for (int mt = 0; mt < 2; ++mt)
#pragma unroll
        for (int r = 0; r < 4; ++r) st[mt][r] = 0.f;

    const short8 zf = {0, 0, 0, 0, 0, 0, 0, 0};
#pragma unroll
    for (int u = 0; u < NT1; ++u) {
        float bv[2][4];
#pragma unroll
        for (int mt = 0; mt < 2; ++mt)
#pragma unroll
            for (int r = 0; r < 4; ++r)
                bv[mt][r] = biasL[(w * 32 + mt * 16 + lg * 4 + r) * NT1 + u];
        const unsigned short* Yu = &Ybf[u * (NBW * PK)];
        const short8 b0 = *(const short8*)&Yu[lr * PK + lg * 8];
        short8 b1 = zf;
        if (lg == 0) b1 = *(const short8*)&Yu[lr * PK + 32];
#pragma unroll
        for (int mt = 0; mt < 2; ++mt) {
            f32x4 z = {0.f, 0.f, 0.f, 0.f};
            z = __builtin_amdgcn_mfma_f32_16x16x32_bf16(afr[mt][0], b0, z, 0, 0, 0);
            z = __builtin_amdgcn_mfma_f32_16x16x32_bf16(afr[mt][1], b1, z, 0, 0, 0);
#pragma unroll
            for (int r = 0; r < 4; ++r)
                st[mt][r] += fc4r[u] * fmaxf(z[r] + bv[mt][r], 0.f);
        }
    }

    // ---------------- epilogue: out[o,b] = sum_t W12[o,t]*st --------------
    float po[NO0];
#pragma unroll
    for (int o = 0; o < NO0; ++o) {
        float a = 0.f;
#pragma unroll
        for (int mt = 0; mt < 2; ++mt)
#pragma unroll
            for (int r = 0; r < 4; ++r)
                a = fmaf(w12L[o * 128 + (w * 32 + mt * 16 + lg * 4 + r)],
                         st[mt][r], a);
        a += __shfl_xor(a, 16, 64);
        a += __shfl_xor(a, 32, 64);
        po[o] = a;
    }
    if (l < 16) {
#pragma unroll
        for (int o = 0; o < NO0; ++o)
            redL[(w * NO0 + o) * NBW + l] = po[o];
    }
    __syncthreads();

    if (tid < NO0 * NBW) {                    // 48 threads
        const int o  = tid >> 4;
        const int bc = tid & 15;
        const float s = redL[(0 * NO0 + o) * NBW + bc]
                      + redL[(1 * NO0 + o) * NBW + bc]
                      + redL[(2 * NO0 + o) * NBW + bc]
                      + redL[(3 * NO0 + o) * NBW + bc]
                      + b2L[o];
        out[((size_t)wg * NBW + bc) * NO0 + o] = s;
    }
}

extern "C" void kernel_launch(void* const* d_in, const int* in_sizes, int n_in,
                              void* d_out, int out_size, void* d_ws, size_t ws_size,
                              hipStream_t stream) {
    const float* x      = (const float*)d_in[0];
    const float* W11    = (const float*)d_in[1];
    const float* fc2_w  = (const float*)d_in[2];
    const float* bias1  = (const float*)d_in[3];
    const float* W12    = (const float*)d_in[4];
    const float* fc4_w  = (const float*)d_in[5];
    const float* bias2  = (const float*)d_in[6];
    float* out = (float*)d_out;

    const int blocks = NB / NBW;   // 8192
    BL_36721970381090_kernel<<<blocks, 256, 0, stream>>>(
        x, W11, fc2_w, bias1, W12, fc4_w, bias2, out);
}

// Round 18
// 58.859 us; speedup vs baseline: 1.0926x; 1.0597x over previous
//
#include <hip/hip_runtime.h>

// Problem sizes
#define NB  131072
#define ND1 40
#define ND2 10
#define NT0 120
#define NT1 5
#define NO0 3

#define NBW 16                  // batches per workgroup
#define XTILE (NBW * ND1 * ND2) // 6400 floats
#define PK  40                  // Ybf row pitch (bf16 elems)

typedef __attribute__((ext_vector_type(8))) short  short8;
typedef __attribute__((ext_vector_type(4))) float  f32x4;

static __device__ __forceinline__ unsigned short f2bf(float f) {
    union { float f; unsigned u; } v; v.f = f;
    unsigned r = v.u + 0x7FFFu + ((v.u >> 16) & 1u);
    return (unsigned short)(r >> 16);
}

// One 16-batch tile per 256-thread block; 8192 blocks.
// NO x staging: phase-1 unit q = 20 contiguous floats at x + wg*XTILE + q*20,
// and q==tid makes wave loads near-coalesced (40 unique lines/instr, L1 hits
// for the rest). Removes the stage->vmcnt(0)-drain->compute serialization
// that pinned R15/R16/R17 at ~62 us regardless of residency/pipelining.
//  phase 1: load 5xfloat4 -> y (fp32 VALU) -> bf16 Y[u][b][d] in LDS.
//  phase 2: MFMA bf16: Z[t,b]=sum_d W11[t,d]*Y_u[d,b];
//           st += fc4[u]*relu(Z+bias1).  (t padded to 128, d to 64.)
//  epilogue: out[o,b] = sum_t W12[o,t]*st[t,b].
__global__ __launch_bounds__(256, 2) void BL_36721970381090_kernel(
    const float* __restrict__ x,
    const float* __restrict__ W11,
    const float* __restrict__ fc2_w,
    const float* __restrict__ bias1,
    const float* __restrict__ W12,
    const float* __restrict__ fc4_w,
    const float* __restrict__ bias2,
    float* __restrict__ out)
{
    __shared__ __align__(16) unsigned short Ybf[NT1 * NBW * PK]; //  6400 B
    __shared__ float biasL[128 * NT1];                           //  2560 B
    __shared__ float w12L[NO0 * 128];                            //  1536 B
    __shared__ float b2L[4];
    __shared__ float redL[4 * NO0 * NBW];                        //   768 B

    const int tid = threadIdx.x;
    const int wg  = blockIdx.x;
    const int w   = tid >> 6;   // wave 0..3
    const int l   = tid & 63;
    const int lr  = l & 15;     // A row / B col within 16-tile
    const int lg  = l >> 4;     // k-group

    // ---------------- prologue: constants -> LDS --------------------------
    for (int i = tid; i < 128 * NT1; i += 256)
        biasL[i] = (i < NT0 * NT1) ? bias1[i] : 0.f;
    for (int i = tid; i < NO0 * 128; i += 256) {
        const int o = i >> 7, t = i & 127;
        w12L[i] = (t < NT0) ? W12[o * NT0 + t] : 0.f;
    }
    if (tid < NO0) b2L[tid] = bias2[tid];

    float fc4r[NT1];
#pragma unroll
    for (int u = 0; u < NT1; ++u) fc4r[u] = fc4_w[u];

    // A-fragments: W11 -> bf16, masked (t<120, d<40)
    short8 afr[2][2];
#pragma unroll
    for (int mt = 0; mt < 2; ++mt) {
        const int t  = w * 32 + mt * 16 + lr;
        const int tc = t < NT0 ? t : NT0 - 1;
#pragma unroll
        for (int kk = 0; kk < 2; ++kk) {
            const int cb = kk * 32 + lg * 8;
            const int cc = cb <= 32 ? cb : 0;
            const float4* pw = (const float4*)(W11 + tc * ND1 + cc);
            const float4 w0 = pw[0], w1 = pw[1];
            const bool v = (t < NT0) && (cb <= 32);
            short8 f;
            f[0] = v ? (short)f2bf(w0.x) : (short)0;
            f[1] = v ? (short)f2bf(w0.y) : (short)0;
            f[2] = v ? (short)f2bf(w0.z) : (short)0;
            f[3] = v ? (short)f2bf(w0.w) : (short)0;
            f[4] = v ? (short)f2bf(w1.x) : (short)0;
            f[5] = v ? (short)f2bf(w1.y) : (short)0;
            f[6] = v ? (short)f2bf(w1.z) : (short)0;
            f[7] = v ? (short)f2bf(w1.w) : (short)0;
            afr[mt][kk] = f;
        }
    }

    // ---------------- phase 1: direct global loads -> y -> bf16 Y ---------
    {
        const float* gx = x + (size_t)wg * XTILE;
        unsigned* Yw = (unsigned*)Ybf;
#pragma unroll
        for (int rep = 0; rep < 2; ++rep) {
            const int  q   = (rep == 0) ? tid : 256 + tid;  // (batch,pair) unit
            const bool act = (rep == 0) || (tid < 64);
            if (act) {                                // 320 units of 20 floats
                const int batch = q / 20;
                const int pair  = q - batch * 20;
                float4 xq[5];
                const float4* xr = (const float4*)(gx + q * 20);
#pragma unroll
                for (int i = 0; i < 5; ++i) xq[i] = xr[i];
                const float* xv = (const float*)xq;
#pragma unroll
                for (int u = 0; u < NT1; ++u) {
                    float a0 = 0.f, a1 = 0.f;
#pragma unroll
                    for (int s = 0; s < ND2; ++s) {
                        const float fw = fc2_w[u * ND2 + s];   // uniform: s_load
                        a0 = fmaf(xv[s], fw, a0);
                        a1 = fmaf(xv[10 + s], fw, a1);
                    }
                    Yw[u * (NBW * PK / 2) + batch * (PK / 2) + pair] =
                        (unsigned)f2bf(a0) | ((unsigned)f2bf(a1) << 16);
                }
            }
        }
    }
    __syncthreads();   // Ybf + constants visible

    // ---------------- phase 2: MFMA + fused relu/fc4 ----------------------
    float st[2][4];
#pragma unroll
    for (int mt = 0; mt < 2; ++mt)
#pragma unroll
        for (int r = 0; r < 4; ++r) st[mt][r] = 0.f;

    const short8 zf = {0, 0, 0, 0, 0, 0, 0, 0};
#pragma unroll
    for (int u = 0; u < NT1; ++u) {
        float bv[2][4];
#pragma unroll
        for (int mt = 0; mt < 2; ++mt)
#pragma unroll
            for (int r = 0; r < 4; ++r)
                bv[mt][r] = biasL[(w * 32 + mt * 16 + lg * 4 + r) * NT1 + u];
        const unsigned short* Yu = &Ybf[u * (NBW * PK)];
        const short8 b0 = *(const short8*)&Yu[lr * PK + lg * 8];
        short8 b1 = zf;
        if (lg == 0) b1 = *(const short8*)&Yu[lr * PK + 32];
#pragma unroll
        for (int mt = 0; mt < 2; ++mt) {
            f32x4 z = {0.f, 0.f, 0.f, 0.f};
            z = __builtin_amdgcn_mfma_f32_16x16x32_bf16(afr[mt][0], b0, z, 0, 0, 0);
            z = __builtin_amdgcn_mfma_f32_16x16x32_bf16(afr[mt][1], b1, z, 0, 0, 0);
#pragma unroll
            for (int r = 0; r < 4; ++r)
                st[mt][r] += fc4r[u] * fmaxf(z[r] + bv[mt][r], 0.f);
        }
    }

    // ---------------- epilogue: out[o,b] = sum_t W12[o,t]*st --------------
    float po[NO0];
#pragma unroll
    for (int o = 0; o < NO0; ++o) {
        float a = 0.f;
#pragma unroll
        for (int mt = 0; mt < 2; ++mt)
#pragma unroll
            for (int r = 0; r < 4; ++r)
                a = fmaf(w12L[o * 128 + (w * 32 + mt * 16 + lg * 4 + r)],
                         st[mt][r], a);
        a += __shfl_xor(a, 16, 64);
        a += __shfl_xor(a, 32, 64);
        po[o] = a;
    }
    if (l < 16) {
#pragma unroll
        for (int o = 0; o < NO0; ++o)
            redL[(w * NO0 + o) * NBW + l] = po[o];
    }
    __syncthreads();

    if (tid < NO0 * NBW) {                    // 48 threads
        const int o  = tid >> 4;
        const int bc = tid & 15;
        const float s = redL[(0 * NO0 + o) * NBW + bc]
                      + redL[(1 * NO0 + o) * NBW + bc]
                      + redL[(2 * NO0 + o) * NBW + bc]
                      + redL[(3 * NO0 + o) * NBW + bc]
                      + b2L[o];
        out[((size_t)wg * NBW + bc) * NO0 + o] = s;
    }
}

extern "C" void kernel_launch(void* const* d_in, const int* in_sizes, int n_in,
                              void* d_out, int out_size, void* d_ws, size_t ws_size,
                              hipStream_t stream) {
    const float* x      = (const float*)d_in[0];
    const float* W11    = (const float*)d_in[1];
    const float* fc2_w  = (const float*)d_in[2];
    const float* bias1  = (const float*)d_in[3];
    const float* W12    = (const float*)d_in[4];
    const float* fc4_w  = (const float*)d_in[5];
    const float* bias2  = (const float*)d_in[6];
    float* out = (float*)d_out;

    const int blocks = NB / NBW;   // 8192
    BL_36721970381090_kernel<<<blocks, 256, 0, stream>>>(
        x, W11, fc2_w, bias1, W12, fc4_w, bias2, out);
}

// Round 19
// 50.714 us; speedup vs baseline: 1.2681x; 1.1606x over previous
//
#include <hip/hip_runtime.h>

// Problem sizes
#define NB  131072
#define ND1 40
#define ND2 10
#define NT0 120
#define NT1 5
#define NO0 3

#define NBW 32                  // batches per workgroup
#define XTILE (NBW * ND1 * ND2) // 12800 floats
#define PK  40                  // Ybf row pitch (bf16 elems)

typedef __attribute__((ext_vector_type(8))) short  short8;
typedef __attribute__((ext_vector_type(4))) float  f32x4;

static __device__ __forceinline__ unsigned short f2bf(float f) {
    union { float f; unsigned u; } v; v.f = f;
    unsigned r = v.u + 0x7FFFu + ((v.u >> 16) & 1u);
    return (unsigned short)(r >> 16);
}

// One 32-batch tile per 256-thread block; 4096 blocks. Direct global loads
// (no staging — R18 beat staged R15). NBW=32 doubles per-thread load depth:
// 2.5 units (up to ~200 B) issued before first use, raising time-integrated
// bytes-in-flight per CU toward the Little's-law requirement for ~6 TB/s.
//  phase 1: load 5xfloat4/unit -> y (fp32 VALU) -> bf16 Y[u][b][d] in LDS.
//  phase 2: MFMA bf16: Z[t,b]=sum_d W11[t,d]*Y_u[d,b];
//           st += fc4[u]*relu(Z+bias1).  (t padded to 128, d to 64.)
//  epilogue: out[o,b] = sum_t W12[o,t]*st[t,b].
__global__ __launch_bounds__(256, 2) void BL_36721970381090_kernel(
    const float* __restrict__ x,
    const float* __restrict__ W11,
    const float* __restrict__ fc2_w,
    const float* __restrict__ bias1,
    const float* __restrict__ W12,
    const float* __restrict__ fc4_w,
    const float* __restrict__ bias2,
    float* __restrict__ out)
{
    __shared__ __align__(16) unsigned short Ybf[NT1 * NBW * PK]; // 12800 B
    __shared__ float biasL[128 * NT1];                           //  2560 B
    __shared__ float w12L[NO0 * 128];                            //  1536 B
    __shared__ float b2L[4];
    __shared__ float redL[4 * NO0 * NBW];                        //  1536 B

    const int tid = threadIdx.x;
    const int wg  = blockIdx.x;
    const int w   = tid >> 6;   // wave 0..3
    const int l   = tid & 63;
    const int lr  = l & 15;     // A row / B col within 16-tile
    const int lg  = l >> 4;     // k-group

    // ---------------- prologue: constants -> LDS --------------------------
    for (int i = tid; i < 128 * NT1; i += 256)
        biasL[i] = (i < NT0 * NT1) ? bias1[i] : 0.f;
    for (int i = tid; i < NO0 * 128; i += 256) {
        const int o = i >> 7, t = i & 127;
        w12L[i] = (t < NT0) ? W12[o * NT0 + t] : 0.f;
    }
    if (tid < NO0) b2L[tid] = bias2[tid];

    float fc4r[NT1];
#pragma unroll
    for (int u = 0; u < NT1; ++u) fc4r[u] = fc4_w[u];

    // A-fragments: W11 -> bf16, masked (t<120, d<40)
    short8 afr[2][2];
#pragma unroll
    for (int mt = 0; mt < 2; ++mt) {
        const int t  = w * 32 + mt * 16 + lr;
        const int tc = t < NT0 ? t : NT0 - 1;
#pragma unroll
        for (int kk = 0; kk < 2; ++kk) {
            const int cb = kk * 32 + lg * 8;
            const int cc = cb <= 32 ? cb : 0;
            const float4* pw = (const float4*)(W11 + tc * ND1 + cc);
            const float4 w0 = pw[0], w1 = pw[1];
            const bool v = (t < NT0) && (cb <= 32);
            short8 f;
            f[0] = v ? (short)f2bf(w0.x) : (short)0;
            f[1] = v ? (short)f2bf(w0.y) : (short)0;
            f[2] = v ? (short)f2bf(w0.z) : (short)0;
            f[3] = v ? (short)f2bf(w0.w) : (short)0;
            f[4] = v ? (short)f2bf(w1.x) : (short)0;
            f[5] = v ? (short)f2bf(w1.y) : (short)0;
            f[6] = v ? (short)f2bf(w1.z) : (short)0;
            f[7] = v ? (short)f2bf(w1.w) : (short)0;
            afr[mt][kk] = f;
        }
    }

    // ---------------- phase 1: direct global loads -> y -> bf16 Y ---------
    {
        const float* gx = x + (size_t)wg * XTILE;
        unsigned* Yw = (unsigned*)Ybf;
#pragma unroll
        for (int rep = 0; rep < 3; ++rep) {
            const int  q   = rep * 256 + tid;           // (batch,pair) unit
            const bool act = (rep < 2) || (tid < 128);  // 640 units total
            if (act) {
                const int batch = q / 20;
                const int pair  = q - batch * 20;
                float4 xq[5];
                const float4* xr = (const float4*)(gx + q * 20);
#pragma unroll
                for (int i = 0; i < 5; ++i) xq[i] = xr[i];
                const float* xv = (const float*)xq;
#pragma unroll
                for (int u = 0; u < NT1; ++u) {
                    float a0 = 0.f, a1 = 0.f;
#pragma unroll
                    for (int s = 0; s < ND2; ++s) {
                        const float fw = fc2_w[u * ND2 + s];   // uniform: s_load
                        a0 = fmaf(xv[s], fw, a0);
                        a1 = fmaf(xv[10 + s], fw, a1);
                    }
                    Yw[u * (NBW * PK / 2) + batch * (PK / 2) + pair] =
                        (unsigned)f2bf(a0) | ((unsigned)f2bf(a1) << 16);
                }
            }
        }
    }
    __syncthreads();   // Ybf + constants visible

    // ---------------- phase 2: MFMA + fused relu/fc4 ----------------------
    float st[2][2][4];          // [m-tile][n-tile][reg]
#pragma unroll
    for (int mt = 0; mt < 2; ++mt)
#pragma unroll
        for (int nt = 0; nt < 2; ++nt)
#pragma unroll
            for (int r = 0; r < 4; ++r) st[mt][nt][r] = 0.f;

    const short8 zf = {0, 0, 0, 0, 0, 0, 0, 0};
#pragma unroll
    for (int u = 0; u < NT1; ++u) {
        float bv[2][4];
#pragma unroll
        for (int mt = 0; mt < 2; ++mt)
#pragma unroll
            for (int r = 0; r < 4; ++r)
                bv[mt][r] = biasL[(w * 32 + mt * 16 + lg * 4 + r) * NT1 + u];
        const unsigned short* Yu = &Ybf[u * (NBW * PK)];
#pragma unroll
        for (int nt = 0; nt < 2; ++nt) {
            const short8 b0 = *(const short8*)&Yu[(nt * 16 + lr) * PK + lg * 8];
            short8 b1 = zf;
            if (lg == 0) b1 = *(const short8*)&Yu[(nt * 16 + lr) * PK + 32];
#pragma unroll
            for (int mt = 0; mt < 2; ++mt) {
                f32x4 z = {0.f, 0.f, 0.f, 0.f};
                z = __builtin_amdgcn_mfma_f32_16x16x32_bf16(afr[mt][0], b0, z, 0, 0, 0);
                z = __builtin_amdgcn_mfma_f32_16x16x32_bf16(afr[mt][1], b1, z, 0, 0, 0);
#pragma unroll
                for (int r = 0; r < 4; ++r)
                    st[mt][nt][r] += fc4r[u] * fmaxf(z[r] + bv[mt][r], 0.f);
            }
        }
    }

    // ---------------- epilogue: out[o,b] = sum_t W12[o,t]*st --------------
    float po[2][NO0];
#pragma unroll
    for (int nt = 0; nt < 2; ++nt)
#pragma unroll
        for (int o = 0; o < NO0; ++o) {
            float a = 0.f;
#pragma unroll
            for (int mt = 0; mt < 2; ++mt)
#pragma unroll
                for (int r = 0; r < 4; ++r)
                    a = fmaf(w12L[o * 128 + (w * 32 + mt * 16 + lg * 4 + r)],
                             st[mt][nt][r], a);
            a += __shfl_xor(a, 16, 64);
            a += __shfl_xor(a, 32, 64);
            po[nt][o] = a;
        }
    if (l < 16) {
#pragma unroll
        for (int nt = 0; nt < 2; ++nt)
#pragma unroll
            for (int o = 0; o < NO0; ++o)
                redL[(w * NO0 + o) * NBW + nt * 16 + l] = po[nt][o];
    }
    __syncthreads();

    if (tid < NO0 * NBW) {                    // 96 threads
        const int o  = tid >> 5;
        const int bc = tid & 31;
        const float s = redL[(0 * NO0 + o) * NBW + bc]
                      + redL[(1 * NO0 + o) * NBW + bc]
                      + redL[(2 * NO0 + o) * NBW + bc]
                      + redL[(3 * NO0 + o) * NBW + bc]
                      + b2L[o];
        out[((size_t)wg * NBW + bc) * NO0 + o] = s;
    }
}

extern "C" void kernel_launch(void* const* d_in, const int* in_sizes, int n_in,
                              void* d_out, int out_size, void* d_ws, size_t ws_size,
                              hipStream_t stream) {
    const float* x      = (const float*)d_in[0];
    const float* W11    = (const float*)d_in[1];
    const float* fc2_w  = (const float*)d_in[2];
    const float* bias1  = (const float*)d_in[3];
    const float* W12    = (const float*)d_in[4];
    const float* fc4_w  = (const float*)d_in[5];
    const float* bias2  = (const float*)d_in[6];
    float* out = (float*)d_out;

    const int blocks = NB / NBW;   // 4096
    BL_36721970381090_kernel<<<blocks, 256, 0, stream>>>(
        x, W11, fc2_w, bias1, W12, fc4_w, bias2, out);
}